// Round 5
// baseline (163.921 us; speedup 1.0000x reference)
//
#include <hip/hip_runtime.h>
#include <hip/hip_bf16.h>

// ---------------------------------------------------------------------------
// EnhancedMultiHeadAttention on MI355X (gfx950)
// B=2, S=2048, D=1024, H=16, dk=64. fp32 in/out, bf16 MFMA compute.
// Round 5: attn QBLK=32/wave (2 q-frags amortize K/V LDS reads), 2-wave
// blocks grid(32,32), stride-72 LDS (bank-staggered, no XOR), deferred
// l-sum, lazy max reduction, XCD swizzle on attn + GEMMs.
// ---------------------------------------------------------------------------

#define S_LEN 2048
#define D_MODEL 1024
#define NHEADS 16
#define DK 64
#define BATCH 2
#define M_ROWS (BATCH * S_LEN)   // 4096
#define LOG2E 1.4426950408889634f
#define LSTR 72                   // LDS row stride in shorts (144B, 16B-aligned)

typedef float f32x4 __attribute__((ext_vector_type(4)));
typedef short s16x8 __attribute__((ext_vector_type(8)));
typedef unsigned short u16x8 __attribute__((ext_vector_type(8)));
typedef unsigned u32x2 __attribute__((ext_vector_type(2)));

__device__ __forceinline__ unsigned short f2bf(float f) {
    unsigned u = __builtin_bit_cast(unsigned, f);
    u = (u + 0x7FFFu + ((u >> 16) & 1u)) >> 16;
    return (unsigned short)u;
}

__device__ __forceinline__ float fast_exp2(float x) {
    float r;
    asm("v_exp_f32 %0, %1" : "=v"(r) : "v"(x));
    return r;
}

__device__ __forceinline__ unsigned cvt_pk_bf16(float a, float b) {
    unsigned r;
    asm("v_cvt_pk_bf16_f32 %0, %1, %2" : "=v"(r) : "v"(a), "v"(b));
    return r;
}

__device__ __forceinline__ float max3f(float a, float b, float c) {
    float r;
    asm("v_max3_f32 %0, %1, %2, %3" : "=v"(r) : "v"(a), "v"(b), "v"(c));
    return r;
}

#define GLD16(gptr, lptr)                                                     \
    __builtin_amdgcn_global_load_lds(                                         \
        (const __attribute__((address_space(1))) void*)(gptr),                \
        (__attribute__((address_space(3))) void*)(lptr), 16, 0, 0)

// ---------------------------------------------------------------------------
// Mask table in exp2 domain
// ---------------------------------------------------------------------------
__global__ void mask_kernel(float* __restrict__ mtab) {
    int d = blockIdx.x * 256 + threadIdx.x;
    if (d < S_LEN) {
        float d2 = (float)d * (float)d;
        mtab[d] = LOG2E * 0.25f * (__expf(-d2 * (1.0f / 50.0f)) +
                                   __expf(-d2 * (1.0f / 200.0f)) +
                                   __expf(-d2 * (1.0f / 800.0f)) +
                                   __expf(-d2 * (1.0f / 3200.0f)));
    }
}

// ---------------------------------------------------------------------------
// fp32 -> bf16 conversion of Q,K,V,Wq,Wk,Wv,Wo (each element exactly once)
// ---------------------------------------------------------------------------
__global__ __launch_bounds__(256) void convert_kernel(
    const float* __restrict__ Q, const float* __restrict__ K,
    const float* __restrict__ V,
    const float* __restrict__ Wq, const float* __restrict__ Wk,
    const float* __restrict__ Wv, const float* __restrict__ Wo,
    unsigned short* __restrict__ Qb, unsigned short* __restrict__ Kb,
    unsigned short* __restrict__ Vb,
    unsigned short* __restrict__ Wqb, unsigned short* __restrict__ Wkb,
    unsigned short* __restrict__ Wvb, unsigned short* __restrict__ Wob)
{
    const int XN = M_ROWS * D_MODEL / 8;
    const int WN = D_MODEL * D_MODEL / 8;
    int i = blockIdx.x * 256 + threadIdx.x;
    const float* src;
    unsigned short* dst;
    int off;
    if (i < 3 * XN) {
        if (i < XN)          { src = Q; dst = Qb; off = i; }
        else if (i < 2 * XN) { src = K; dst = Kb; off = i - XN; }
        else                 { src = V; dst = Vb; off = i - 2 * XN; }
    } else {
        int j = i - 3 * XN;
        if (j < WN)          { src = Wq; dst = Wqb; off = j; }
        else if (j < 2 * WN) { src = Wk; dst = Wkb; off = j - WN; }
        else if (j < 3 * WN) { src = Wv; dst = Wvb; off = j - 2 * WN; }
        else                 { src = Wo; dst = Wob; off = j - 3 * WN; }
    }
    f32x4 v0 = *(const f32x4*)(src + (size_t)off * 8);
    f32x4 v1 = *(const f32x4*)(src + (size_t)off * 8 + 4);
    s16x8 o;
#pragma unroll
    for (int j = 0; j < 4; ++j) {
        o[j]     = (short)f2bf(v0[j]);
        o[j + 4] = (short)f2bf(v1[j]);
    }
    *(s16x8*)(dst + (size_t)off * 8) = o;
}

// ---------------------------------------------------------------------------
// m97-structure GEMM core: C[128x128] = A[128xK] @ B[128xK]^T  (bf16 inputs)
// ---------------------------------------------------------------------------
__device__ __forceinline__ void gemm_core_128(
    const unsigned short* __restrict__ A, const unsigned short* __restrict__ B,
    unsigned short* As, unsigned short* Bs,
    int m0, int n0, int K, int tid, f32x4 acc[4][4])
{
    const int wid  = tid >> 6;
    const int lane = tid & 63;
    const int g    = lane >> 4;
    const int c    = lane & 15;
    const int wm   = wid >> 1;
    const int wn   = wid & 1;

    const int srow   = tid >> 3;
    const int schunk = tid & 7;

    for (int kt = 0; kt < K / 64; ++kt) {
        const int k0 = kt * 64;
        __syncthreads();
#pragma unroll
        for (int r = 0; r < 4; ++r) {
            const int row = r * 32 + srow;
            GLD16(A + (size_t)(m0 + row) * K + k0 + schunk * 8,
                  &As[(r * 256 + wid * 64) * 8]);
        }
#pragma unroll
        for (int r = 0; r < 4; ++r) {
            const int row = r * 32 + srow;
            GLD16(B + (size_t)(n0 + row) * K + k0 + schunk * 8,
                  &Bs[(r * 256 + wid * 64) * 8]);
        }
        __syncthreads();

        s16x8 a[2][4];
#pragma unroll
        for (int ks = 0; ks < 2; ++ks)
#pragma unroll
            for (int mf = 0; mf < 4; ++mf)
                a[ks][mf] = *(const s16x8*)
                    &As[(wm * 64 + mf * 16 + c) * 64 + ks * 32 + g * 8];
#pragma unroll
        for (int ks = 0; ks < 2; ++ks) {
#pragma unroll
            for (int nf = 0; nf < 4; ++nf) {
                s16x8 b = *(const s16x8*)
                    &Bs[(wn * 64 + nf * 16 + c) * 64 + ks * 32 + g * 8];
#pragma unroll
                for (int mf = 0; mf < 4; ++mf)
                    acc[mf][nf] = __builtin_amdgcn_mfma_f32_16x16x32_bf16(
                        a[ks][mf], b, acc[mf][nf], 0, 0, 0);
            }
        }
    }
}

// ---------------------------------------------------------------------------
// QKV projection: Y = X @ W^T + b -> bf16 head layout [B][H][S][dk]
// ---------------------------------------------------------------------------
__global__ __launch_bounds__(256) void proj_gemm(
    const unsigned short* __restrict__ Qx, const unsigned short* __restrict__ Kx,
    const unsigned short* __restrict__ Vx,
    const unsigned short* __restrict__ Wq, const unsigned short* __restrict__ Wk,
    const unsigned short* __restrict__ Wv,
    const float* __restrict__ bq, const float* __restrict__ bk,
    const float* __restrict__ bv,
    unsigned short* __restrict__ qo, unsigned short* __restrict__ ko,
    unsigned short* __restrict__ vo)
{
    const int z = blockIdx.z;
    const unsigned short* X = (z == 0) ? Qx : (z == 1) ? Kx : Vx;
    const unsigned short* W = (z == 0) ? Wq : (z == 1) ? Wk : Wv;
    const float* bias       = (z == 0) ? bq : (z == 1) ? bk : bv;
    unsigned short* out     = (z == 0) ? qo : (z == 1) ? ko : vo;
    const float scale = (z == 0) ? (0.125f * LOG2E) : 1.0f;

    __shared__ unsigned short As[128 * 64];
    __shared__ unsigned short Bs[128 * 64];

    const int tid = threadIdx.x;
    // XCD swizzle: nwg = 256 per z, chunk 32 per XCD (= one full B-panel row)
    const int flat = blockIdx.y * 32 + blockIdx.x;
    const int sw   = (flat & 7) * 32 + (flat >> 3);
    const int m0   = (sw & 31) * 128;
    const int n0   = (sw >> 5) * 128;

    f32x4 acc[4][4];
#pragma unroll
    for (int i = 0; i < 4; ++i)
#pragma unroll
        for (int j = 0; j < 4; ++j) acc[i][j] = (f32x4){0.f, 0.f, 0.f, 0.f};

    gemm_core_128(X, W, As, Bs, m0, n0, D_MODEL, tid, acc);

    const int lane = tid & 63;
    const int g    = lane >> 4;
    const int c    = lane & 15;
    const int wm   = (tid >> 6) >> 1;
    const int wn   = (tid >> 6) & 1;

#pragma unroll
    for (int mf = 0; mf < 4; ++mf) {
#pragma unroll
        for (int nf = 0; nf < 4; ++nf) {
            const int o = n0 + wn * 64 + nf * 16 + c;
            const float bv_ = bias[o];
            const int h  = o >> 6;
            const int dd = o & 63;
#pragma unroll
            for (int r = 0; r < 4; ++r) {
                const int m = m0 + wm * 64 + mf * 16 + g * 4 + r;
                const int b = m >> 11;
                const int s = m & (S_LEN - 1);
                const float val = (acc[mf][nf][r] + bv_) * scale;
                out[(((size_t)(b * NHEADS + h)) * S_LEN + s) * DK + dd] = f2bf(val);
            }
        }
    }
}

// ---------------------------------------------------------------------------
// Output projection: Y = A @ Wo^T + bo  (fp32 out)
// ---------------------------------------------------------------------------
__global__ __launch_bounds__(256) void out_gemm(
    const unsigned short* __restrict__ A,
    const unsigned short* __restrict__ W,
    const float* __restrict__ bias,
    float* __restrict__ out)
{
    __shared__ unsigned short As[128 * 64];
    __shared__ unsigned short Bs[128 * 64];

    const int tid = threadIdx.x;
    const int flat = blockIdx.y * 32 + blockIdx.x;
    const int sw   = (flat & 7) * 32 + (flat >> 3);
    const int m0   = (sw & 31) * 128;
    const int n0   = (sw >> 5) * 128;

    f32x4 acc[4][4];
#pragma unroll
    for (int i = 0; i < 4; ++i)
#pragma unroll
        for (int j = 0; j < 4; ++j) acc[i][j] = (f32x4){0.f, 0.f, 0.f, 0.f};

    gemm_core_128(A, W, As, Bs, m0, n0, D_MODEL, tid, acc);

    const int lane = tid & 63;
    const int g    = lane >> 4;
    const int c    = lane & 15;
    const int wm   = (tid >> 6) >> 1;
    const int wn   = (tid >> 6) & 1;

#pragma unroll
    for (int mf = 0; mf < 4; ++mf) {
#pragma unroll
        for (int nf = 0; nf < 4; ++nf) {
            const int o = n0 + wn * 64 + nf * 16 + c;
            const float bv_ = bias[o];
#pragma unroll
            for (int r = 0; r < 4; ++r) {
                const int m = m0 + wm * 64 + mf * 16 + g * 4 + r;
                out[(size_t)m * D_MODEL + o] = acc[mf][nf][r] + bv_;
            }
        }
    }
}

// ---------------------------------------------------------------------------
// Flash attention: 2 waves x 32 q-rows, KBLK=64, swapped QK^T, stride-72 LDS.
// grid (S/64, B*H) XCD-swizzled, 128 threads.
// ---------------------------------------------------------------------------
__global__ __launch_bounds__(128) void attn_kernel(
    const unsigned short* __restrict__ qh,
    const unsigned short* __restrict__ kh,
    const unsigned short* __restrict__ vh,
    const float* __restrict__ mask_tab,
    unsigned short* __restrict__ attn_out)
{
    __shared__ float mtab[S_LEN];                 // 8 KB
    __shared__ unsigned short Kt[64 * LSTR];      // 9 KB
    __shared__ unsigned short Vt[64 * LSTR];      // 9 KB  (V^T: [d][k])
    __shared__ unsigned short Pt[2][32 * LSTR];   // 9 KB  (per-wave P)

    const int tid  = threadIdx.x;
    const int wid  = tid >> 6;
    const int lane = tid & 63;
    const int g    = lane >> 4;
    const int c    = lane & 15;

    // XCD swizzle: nwg = 1024, chunk 128 per XCD (= 4 heads' K/V in one L2)
    const int flat = blockIdx.y * 32 + blockIdx.x;
    const int sw   = (flat & 7) * 128 + (flat >> 3);
    const int bh   = sw >> 5;
    const int bx   = sw & 31;
    const int b    = bh >> 4;
    const int h    = bh & 15;
    const int q0w  = bx * 64 + wid * 32;

    // mask table -> LDS (128 threads x 16 floats)
#pragma unroll
    for (int i = 0; i < 4; ++i)
        *(f32x4*)&mtab[tid * 16 + i * 4] = *(const f32x4*)&mask_tab[tid * 16 + i * 4];

    const size_t head_off = (size_t)bh * S_LEN * DK;
    const unsigned short* qp = qh + head_off;
    const unsigned short* kp = kh + head_off;
    const unsigned short* vp = vh + head_off;

    // Q fragments (B-operand of swapped QK^T): 2 q-frags of 16 rows
    s16x8 aq[2][2];
#pragma unroll
    for (int qf = 0; qf < 2; ++qf) {
        const unsigned short* qrow = qp + (size_t)(q0w + qf * 16 + c) * DK;
        aq[qf][0] = *(const s16x8*)(qrow + g * 8);
        aq[qf][1] = *(const s16x8*)(qrow + 32 + g * 8);
    }

    f32x4 acc_o[2][4];
#pragma unroll
    for (int qf = 0; qf < 2; ++qf)
#pragma unroll
        for (int nf = 0; nf < 4; ++nf) acc_o[qf][nf] = (f32x4){0.f, 0.f, 0.f, 0.f};
    float m_l[2] = {-1e30f, -1e30f};
    f32x4 lsum[2];
    lsum[0] = (f32x4){0.f, 0.f, 0.f, 0.f};
    lsum[1] = (f32x4){0.f, 0.f, 0.f, 0.f};

    // staging decomposition (128 threads, 64x64 tile each for K and V)
    const int krow = tid >> 1;           // 0..63
    const int kcol = (tid & 1) * 32;     // element offset in row
    const int vd0  = (tid & 31) * 2;     // d row pair
    const int vk16 = (tid >> 5) * 16;    // k base (0..48)

    s16x8 kreg[4];
    unsigned vreg[16];
#pragma unroll
    for (int i = 0; i < 4; ++i)
        kreg[i] = *(const s16x8*)&kp[(size_t)krow * DK + kcol + i * 8];
#pragma unroll
    for (int i = 0; i < 16; ++i)
        vreg[i] = *(const unsigned*)&vp[(size_t)(vk16 + i) * DK + vd0];

    unsigned short* Ptw = Pt[wid];

    for (int kt = 0; kt < S_LEN / 64; ++kt) {
        const int k0 = kt * 64;
        __syncthreads();   // previous tile's LDS reads done

        // ---- staged registers -> LDS ----
#pragma unroll
        for (int i = 0; i < 4; ++i)
            *(s16x8*)&Kt[krow * LSTR + kcol + i * 8] = kreg[i];
        {
            u16x8 p0, p1, p2, p3;
#pragma unroll
            for (int i = 0; i < 8; ++i) {
                p0[i] = (unsigned short)vreg[i];
                p1[i] = (unsigned short)vreg[8 + i];
                p2[i] = (unsigned short)(vreg[i] >> 16);
                p3[i] = (unsigned short)(vreg[8 + i] >> 16);
            }
            *(u16x8*)&Vt[vd0 * LSTR + vk16]           = p0;
            *(u16x8*)&Vt[vd0 * LSTR + vk16 + 8]       = p1;
            *(u16x8*)&Vt[(vd0 + 1) * LSTR + vk16]     = p2;
            *(u16x8*)&Vt[(vd0 + 1) * LSTR + vk16 + 8] = p3;
        }
        // ---- prefetch next tile ----
        if (kt < S_LEN / 64 - 1) {
            const int k1 = k0 + 64;
#pragma unroll
            for (int i = 0; i < 4; ++i)
                kreg[i] = *(const s16x8*)&kp[(size_t)(k1 + krow) * DK + kcol + i * 8];
#pragma unroll
            for (int i = 0; i < 16; ++i)
                vreg[i] = *(const unsigned*)&vp[(size_t)(k1 + vk16 + i) * DK + vd0];
        }
        __syncthreads();   // staging visible

        // ---- QK^T (swapped): lane holds q=c(+16qf), k = nf*16+g*4+r ----
        f32x4 st[2][4];
        __builtin_amdgcn_s_setprio(1);
#pragma unroll
        for (int nf = 0; nf < 4; ++nf) {
            const unsigned short* kr = &Kt[(nf * 16 + c) * LSTR + g * 8];
            s16x8 kf0 = *(const s16x8*)kr;
            s16x8 kf1 = *(const s16x8*)(kr + 32);
            st[0][nf] = __builtin_amdgcn_mfma_f32_16x16x32_bf16(
                kf0, aq[0][0], (f32x4){0.f, 0.f, 0.f, 0.f}, 0, 0, 0);
            st[0][nf] = __builtin_amdgcn_mfma_f32_16x16x32_bf16(
                kf1, aq[0][1], st[0][nf], 0, 0, 0);
            st[1][nf] = __builtin_amdgcn_mfma_f32_16x16x32_bf16(
                kf0, aq[1][0], (f32x4){0.f, 0.f, 0.f, 0.f}, 0, 0, 0);
            st[1][nf] = __builtin_amdgcn_mfma_f32_16x16x32_bf16(
                kf1, aq[1][1], st[1][nf], 0, 0, 0);
        }
        __builtin_amdgcn_s_setprio(0);

        // ---- mask add (near-diagonal tiles only) ----
        const int diff = q0w - k0;
        if (diff >= -31 && diff <= 510) {
#pragma unroll
            for (int qf = 0; qf < 2; ++qf) {
                const int dbase = q0w + qf * 16 + c - k0;
#pragma unroll
                for (int nf = 0; nf < 4; ++nf)
#pragma unroll
                    for (int r = 0; r < 4; ++r) {
                        const int d = dbase - (nf * 16 + g * 4 + r);
                        if (d >= 0) st[qf][nf][r] += mtab[d];
                    }
            }
        }

        // ---- per-qf tile max (local only; cross-lane deferred) ----
        float tm[2];
#pragma unroll
        for (int qf = 0; qf < 2; ++qf) {
            float t = max3f(st[qf][0][0], st[qf][0][1], st[qf][0][2]);
            t = max3f(t, st[qf][0][3], st[qf][1][0]);
            t = max3f(t, st[qf][1][1], st[qf][1][2]);
            t = max3f(t, st[qf][1][3], st[qf][2][0]);
            t = max3f(t, st[qf][2][1], st[qf][2][2]);
            t = max3f(t, st[qf][2][3], st[qf][3][0]);
            t = max3f(t, st[qf][3][1], st[qf][3][2]);
            tm[qf] = fmaxf(t, st[qf][3][3]);
        }

        // ---- defer-max (T13): rescale only when max grew past THR=8 ----
        if (__any(tm[0] > m_l[0] + 8.0f || tm[1] > m_l[1] + 8.0f)) {
#pragma unroll
            for (int qf = 0; qf < 2; ++qf) {
                float t = tm[qf];
                t = fmaxf(t, __shfl_xor(t, 16));
                t = fmaxf(t, __shfl_xor(t, 32));
                const float mnew = fmaxf(m_l[qf], t);
                const float csc  = fast_exp2(m_l[qf] - mnew);
                m_l[qf] = mnew;
                lsum[qf] *= csc;
                f32x4 cscv;
#pragma unroll
                for (int r = 0; r < 4; ++r) cscv[r] = __shfl(csc, g * 4 + r);
#pragma unroll
                for (int nf = 0; nf < 4; ++nf) acc_o[qf][nf] *= cscv;
            }
        }

        // ---- P = exp2(st - m); deferred l accumulation; P store ----
#pragma unroll
        for (int qf = 0; qf < 2; ++qf) {
#pragma unroll
            for (int nf = 0; nf < 4; ++nf)
#pragma unroll
                for (int r = 0; r < 4; ++r)
                    st[qf][nf][r] = fast_exp2(st[qf][nf][r] - m_l[qf]);
            lsum[qf] += (st[qf][0] + st[qf][1]) + (st[qf][2] + st[qf][3]);
#pragma unroll
            for (int nf = 0; nf < 4; ++nf) {
                u32x2 pk;
                pk[0] = cvt_pk_bf16(st[qf][nf][0], st[qf][nf][1]);
                pk[1] = cvt_pk_bf16(st[qf][nf][2], st[qf][nf][3]);
                *(u32x2*)&Ptw[(qf * 16 + c) * LSTR + nf * 16 + g * 4] = pk;
            }
        }

        // ---- PV: O[q][d] += P @ V (V-frags shared across both q-frags) ----
        __builtin_amdgcn_s_setprio(1);
#pragma unroll
        for (int f = 0; f < 2; ++f) {
            s16x8 pa0 = *(const s16x8*)&Ptw[c * LSTR + f * 32 + g * 8];
            s16x8 pa1 = *(const s16x8*)&Ptw[(16 + c) * LSTR + f * 32 + g * 8];
#pragma unroll
            for (int nf = 0; nf < 4; ++nf) {
                s16x8 vb = *(const s16x8*)&Vt[(nf * 16 + c) * LSTR + f * 32 + g * 8];
                acc_o[0][nf] = __builtin_amdgcn_mfma_f32_16x16x32_bf16(
                    pa0, vb, acc_o[0][nf], 0, 0, 0);
                acc_o[1][nf] = __builtin_amdgcn_mfma_f32_16x16x32_bf16(
                    pa1, vb, acc_o[1][nf], 0, 0, 0);
            }
        }
        __builtin_amdgcn_s_setprio(0);
    }

    // epilogue: reduce deferred l, normalize, store bf16
    float lq[2];
#pragma unroll
    for (int qf = 0; qf < 2; ++qf) {
        float l = (lsum[qf][0] + lsum[qf][1]) + (lsum[qf][2] + lsum[qf][3]);
        l += __shfl_xor(l, 16);
        l += __shfl_xor(l, 32);
        lq[qf] = l;
    }
#pragma unroll
    for (int qf = 0; qf < 2; ++qf) {
        f32x4 linv;
#pragma unroll
        for (int r = 0; r < 4; ++r) linv[r] = 1.0f / __shfl(lq[qf], g * 4 + r);
#pragma unroll
        for (int nf = 0; nf < 4; ++nf) {
#pragma unroll
            for (int r = 0; r < 4; ++r) {
                const int i_glob = q0w + qf * 16 + g * 4 + r;
                const int d = nf * 16 + c;
                attn_out[((size_t)(b * S_LEN + i_glob)) * D_MODEL + h * DK + d] =
                    f2bf(acc_o[qf][nf][r] * linv[r]);
            }
        }
    }
}

// ---------------------------------------------------------------------------
extern "C" void kernel_launch(void* const* d_in, const int* in_sizes, int n_in,
                              void* d_out, int out_size, void* d_ws, size_t ws_size,
                              hipStream_t stream) {
    const float* Q  = (const float*)d_in[0];
    const float* K  = (const float*)d_in[1];
    const float* V  = (const float*)d_in[2];
    const float* Wq = (const float*)d_in[3];
    const float* bq = (const float*)d_in[4];
    const float* Wk = (const float*)d_in[5];
    const float* bk = (const float*)d_in[6];
    const float* Wv = (const float*)d_in[7];
    const float* bv = (const float*)d_in[8];
    const float* Wo = (const float*)d_in[9];
    const float* bo = (const float*)d_in[10];
    float* out = (float*)d_out;

    const size_t XE = (size_t)M_ROWS * D_MODEL;
    const size_t WE = (size_t)D_MODEL * D_MODEL;
    unsigned short* qh  = (unsigned short*)d_ws;
    unsigned short* kh  = qh + XE;
    unsigned short* vh  = kh + XE;
    unsigned short* ah  = vh + XE;
    unsigned short* Qb  = ah + XE;
    unsigned short* Kb  = Qb + XE;
    unsigned short* Vb  = Kb + XE;
    unsigned short* Wqb = Vb + XE;
    unsigned short* Wkb = Wqb + WE;
    unsigned short* Wvb = Wkb + WE;
    unsigned short* Wob = Wvb + WE;
    float* mtab = (float*)(Wob + WE);

    mask_kernel<<<dim3(S_LEN / 256), 256, 0, stream>>>(mtab);
    convert_kernel<<<dim3((3 * XE / 8 + 4 * WE / 8) / 256), 256, 0, stream>>>(
        Q, K, V, Wq, Wk, Wv, Wo, Qb, Kb, Vb, Wqb, Wkb, Wvb, Wob);
    proj_gemm<<<dim3(32, 8, 3), 256, 0, stream>>>(
        Qb, Kb, Vb, Wqb, Wkb, Wvb, bq, bk, bv, qh, kh, vh);
    attn_kernel<<<dim3(32, 32), 128, 0, stream>>>(
        qh, kh, vh, mtab, ah);
    out_gemm<<<dim3(32, 8), 256, 0, stream>>>(
        ah, Wob, bo, out);
}

// Round 6
// 135.385 us; speedup vs baseline: 1.2108x; 1.2108x over previous
//
#include <hip/hip_runtime.h>
#include <hip/hip_bf16.h>

// ---------------------------------------------------------------------------
// EnhancedMultiHeadAttention on MI355X (gfx950)
// B=2, S=2048, D=1024, H=16, dk=64. fp32 in/out, bf16 MFMA compute.
// Round 6: attn reverted to R4 structure (512 thr, 8 waves, 16 q/wave, XOR
// swizzle) + XCD swizzle (R5's one win) + deferred l-sum + lazy max.
// mask fused into convert. GEMMs keep R5 XCD swizzle.
// ---------------------------------------------------------------------------

#define S_LEN 2048
#define D_MODEL 1024
#define NHEADS 16
#define DK 64
#define BATCH 2
#define M_ROWS (BATCH * S_LEN)   // 4096
#define LOG2E 1.4426950408889634f

typedef float f32x4 __attribute__((ext_vector_type(4)));
typedef short s16x8 __attribute__((ext_vector_type(8)));
typedef unsigned short u16x4 __attribute__((ext_vector_type(4)));
typedef unsigned u32x2 __attribute__((ext_vector_type(2)));

__device__ __forceinline__ unsigned short f2bf(float f) {
    unsigned u = __builtin_bit_cast(unsigned, f);
    u = (u + 0x7FFFu + ((u >> 16) & 1u)) >> 16;
    return (unsigned short)u;
}

__device__ __forceinline__ float fast_exp2(float x) {
    float r;
    asm("v_exp_f32 %0, %1" : "=v"(r) : "v"(x));
    return r;
}

__device__ __forceinline__ unsigned cvt_pk_bf16(float a, float b) {
    unsigned r;
    asm("v_cvt_pk_bf16_f32 %0, %1, %2" : "=v"(r) : "v"(a), "v"(b));
    return r;
}

__device__ __forceinline__ float max3f(float a, float b, float c) {
    float r;
    asm("v_max3_f32 %0, %1, %2, %3" : "=v"(r) : "v"(a), "v"(b), "v"(c));
    return r;
}

#define GLD16(gptr, lptr)                                                     \
    __builtin_amdgcn_global_load_lds(                                         \
        (const __attribute__((address_space(1))) void*)(gptr),                \
        (__attribute__((address_space(3))) void*)(lptr), 16, 0, 0)

// ---------------------------------------------------------------------------
// fp32 -> bf16 conversion of Q,K,V,Wq,Wk,Wv,Wo + mask table (fused tail)
// ---------------------------------------------------------------------------
__global__ __launch_bounds__(256) void convert_kernel(
    const float* __restrict__ Q, const float* __restrict__ K,
    const float* __restrict__ V,
    const float* __restrict__ Wq, const float* __restrict__ Wk,
    const float* __restrict__ Wv, const float* __restrict__ Wo,
    unsigned short* __restrict__ Qb, unsigned short* __restrict__ Kb,
    unsigned short* __restrict__ Vb,
    unsigned short* __restrict__ Wqb, unsigned short* __restrict__ Wkb,
    unsigned short* __restrict__ Wvb, unsigned short* __restrict__ Wob,
    float* __restrict__ mtab)
{
    const int XN = M_ROWS * D_MODEL / 8;    // 524288
    const int WN = D_MODEL * D_MODEL / 8;   // 131072
    const int TOT = 3 * XN + 4 * WN;        // 2097152
    int i = blockIdx.x * 256 + threadIdx.x;
    if (i >= TOT) {
        // mask table tail: m[d] = log2e * 0.25 * sum_w exp(-d^2/(2 w^2))
        int d = i - TOT;
        if (d < S_LEN) {
            float d2 = (float)d * (float)d;
            mtab[d] = LOG2E * 0.25f * (__expf(-d2 * (1.0f / 50.0f)) +
                                       __expf(-d2 * (1.0f / 200.0f)) +
                                       __expf(-d2 * (1.0f / 800.0f)) +
                                       __expf(-d2 * (1.0f / 3200.0f)));
        }
        return;
    }
    const float* src;
    unsigned short* dst;
    int off;
    if (i < 3 * XN) {
        if (i < XN)          { src = Q; dst = Qb; off = i; }
        else if (i < 2 * XN) { src = K; dst = Kb; off = i - XN; }
        else                 { src = V; dst = Vb; off = i - 2 * XN; }
    } else {
        int j = i - 3 * XN;
        if (j < WN)          { src = Wq; dst = Wqb; off = j; }
        else if (j < 2 * WN) { src = Wk; dst = Wkb; off = j - WN; }
        else if (j < 3 * WN) { src = Wv; dst = Wvb; off = j - 2 * WN; }
        else                 { src = Wo; dst = Wob; off = j - 3 * WN; }
    }
    f32x4 v0 = *(const f32x4*)(src + (size_t)off * 8);
    f32x4 v1 = *(const f32x4*)(src + (size_t)off * 8 + 4);
    s16x8 o;
#pragma unroll
    for (int j = 0; j < 4; ++j) {
        o[j]     = (short)f2bf(v0[j]);
        o[j + 4] = (short)f2bf(v1[j]);
    }
    *(s16x8*)(dst + (size_t)off * 8) = o;
}

// ---------------------------------------------------------------------------
// m97-structure GEMM core: C[128x128] = A[128xK] @ B[128xK]^T  (bf16 inputs)
// ---------------------------------------------------------------------------
__device__ __forceinline__ void gemm_core_128(
    const unsigned short* __restrict__ A, const unsigned short* __restrict__ B,
    unsigned short* As, unsigned short* Bs,
    int m0, int n0, int K, int tid, f32x4 acc[4][4])
{
    const int wid  = tid >> 6;
    const int lane = tid & 63;
    const int g    = lane >> 4;
    const int c    = lane & 15;
    const int wm   = wid >> 1;
    const int wn   = wid & 1;

    const int srow   = tid >> 3;
    const int schunk = tid & 7;

    for (int kt = 0; kt < K / 64; ++kt) {
        const int k0 = kt * 64;
        __syncthreads();
#pragma unroll
        for (int r = 0; r < 4; ++r) {
            const int row = r * 32 + srow;
            GLD16(A + (size_t)(m0 + row) * K + k0 + schunk * 8,
                  &As[(r * 256 + wid * 64) * 8]);
        }
#pragma unroll
        for (int r = 0; r < 4; ++r) {
            const int row = r * 32 + srow;
            GLD16(B + (size_t)(n0 + row) * K + k0 + schunk * 8,
                  &Bs[(r * 256 + wid * 64) * 8]);
        }
        __syncthreads();

        s16x8 a[2][4];
#pragma unroll
        for (int ks = 0; ks < 2; ++ks)
#pragma unroll
            for (int mf = 0; mf < 4; ++mf)
                a[ks][mf] = *(const s16x8*)
                    &As[(wm * 64 + mf * 16 + c) * 64 + ks * 32 + g * 8];
#pragma unroll
        for (int ks = 0; ks < 2; ++ks) {
#pragma unroll
            for (int nf = 0; nf < 4; ++nf) {
                s16x8 b = *(const s16x8*)
                    &Bs[(wn * 64 + nf * 16 + c) * 64 + ks * 32 + g * 8];
#pragma unroll
                for (int mf = 0; mf < 4; ++mf)
                    acc[mf][nf] = __builtin_amdgcn_mfma_f32_16x16x32_bf16(
                        a[ks][mf], b, acc[mf][nf], 0, 0, 0);
            }
        }
    }
}

// ---------------------------------------------------------------------------
// QKV projection: Y = X @ W^T + b -> bf16 head layout [B][H][S][dk]
// ---------------------------------------------------------------------------
__global__ __launch_bounds__(256) void proj_gemm(
    const unsigned short* __restrict__ Qx, const unsigned short* __restrict__ Kx,
    const unsigned short* __restrict__ Vx,
    const unsigned short* __restrict__ Wq, const unsigned short* __restrict__ Wk,
    const unsigned short* __restrict__ Wv,
    const float* __restrict__ bq, const float* __restrict__ bk,
    const float* __restrict__ bv,
    unsigned short* __restrict__ qo, unsigned short* __restrict__ ko,
    unsigned short* __restrict__ vo)
{
    const int z = blockIdx.z;
    const unsigned short* X = (z == 0) ? Qx : (z == 1) ? Kx : Vx;
    const unsigned short* W = (z == 0) ? Wq : (z == 1) ? Wk : Wv;
    const float* bias       = (z == 0) ? bq : (z == 1) ? bk : bv;
    unsigned short* out     = (z == 0) ? qo : (z == 1) ? ko : vo;
    const float scale = (z == 0) ? (0.125f * LOG2E) : 1.0f;

    __shared__ unsigned short As[128 * 64];
    __shared__ unsigned short Bs[128 * 64];

    const int tid = threadIdx.x;
    // XCD swizzle: nwg = 256 per z, chunk 32 per XCD
    const int flat = blockIdx.y * 32 + blockIdx.x;
    const int sw   = (flat & 7) * 32 + (flat >> 3);
    const int m0   = (sw & 31) * 128;
    const int n0   = (sw >> 5) * 128;

    f32x4 acc[4][4];
#pragma unroll
    for (int i = 0; i < 4; ++i)
#pragma unroll
        for (int j = 0; j < 4; ++j) acc[i][j] = (f32x4){0.f, 0.f, 0.f, 0.f};

    gemm_core_128(X, W, As, Bs, m0, n0, D_MODEL, tid, acc);

    const int lane = tid & 63;
    const int g    = lane >> 4;
    const int c    = lane & 15;
    const int wm   = (tid >> 6) >> 1;
    const int wn   = (tid >> 6) & 1;

#pragma unroll
    for (int mf = 0; mf < 4; ++mf) {
#pragma unroll
        for (int nf = 0; nf < 4; ++nf) {
            const int o = n0 + wn * 64 + nf * 16 + c;
            const float bv_ = bias[o];
            const int h  = o >> 6;
            const int dd = o & 63;
#pragma unroll
            for (int r = 0; r < 4; ++r) {
                const int m = m0 + wm * 64 + mf * 16 + g * 4 + r;
                const int b = m >> 11;
                const int s = m & (S_LEN - 1);
                const float val = (acc[mf][nf][r] + bv_) * scale;
                out[(((size_t)(b * NHEADS + h)) * S_LEN + s) * DK + dd] = f2bf(val);
            }
        }
    }
}

// ---------------------------------------------------------------------------
// Output projection: Y = A @ Wo^T + bo  (fp32 out)
// ---------------------------------------------------------------------------
__global__ __launch_bounds__(256) void out_gemm(
    const unsigned short* __restrict__ A,
    const unsigned short* __restrict__ W,
    const float* __restrict__ bias,
    float* __restrict__ out)
{
    __shared__ unsigned short As[128 * 64];
    __shared__ unsigned short Bs[128 * 64];

    const int tid = threadIdx.x;
    const int flat = blockIdx.y * 32 + blockIdx.x;
    const int sw   = (flat & 7) * 32 + (flat >> 3);
    const int m0   = (sw & 31) * 128;
    const int n0   = (sw >> 5) * 128;

    f32x4 acc[4][4];
#pragma unroll
    for (int i = 0; i < 4; ++i)
#pragma unroll
        for (int j = 0; j < 4; ++j) acc[i][j] = (f32x4){0.f, 0.f, 0.f, 0.f};

    gemm_core_128(A, W, As, Bs, m0, n0, D_MODEL, tid, acc);

    const int lane = tid & 63;
    const int g    = lane >> 4;
    const int c    = lane & 15;
    const int wm   = (tid >> 6) >> 1;
    const int wn   = (tid >> 6) & 1;

#pragma unroll
    for (int mf = 0; mf < 4; ++mf) {
#pragma unroll
        for (int nf = 0; nf < 4; ++nf) {
            const int o = n0 + wn * 64 + nf * 16 + c;
            const float bv_ = bias[o];
#pragma unroll
            for (int r = 0; r < 4; ++r) {
                const int m = m0 + wm * 64 + mf * 16 + g * 4 + r;
                out[(size_t)m * D_MODEL + o] = acc[mf][nf][r] + bv_;
            }
        }
    }
}

// ---------------------------------------------------------------------------
// Flash attention, swapped-QK^T (R4 structure + XCD swizzle + lazy softmax).
// grid (S/128, B*H) -> 512 blocks, 8 waves, 16 q-rows/wave, KBLK=64.
// ---------------------------------------------------------------------------
#define VSWZ(row) ((((row) >> 1) & 7) << 4)

__global__ __launch_bounds__(512) void attn_kernel(
    const unsigned short* __restrict__ qh,
    const unsigned short* __restrict__ kh,
    const unsigned short* __restrict__ vh,
    const float* __restrict__ mask_tab,
    unsigned short* __restrict__ attn_out)
{
    __shared__ float mtab[S_LEN];
    __shared__ unsigned short Kt[64 * 64];
    __shared__ unsigned short Vt[64 * 64];
    __shared__ unsigned short Pt[8][16 * 64];

    const int tid  = threadIdx.x;
    const int wid  = tid >> 6;
    const int lane = tid & 63;
    const int g    = lane >> 4;
    const int c    = lane & 15;

    // XCD swizzle: nwg = 512, chunk 64 per XCD (= 4 heads' K/V in one L2)
    const int flat = blockIdx.y * 16 + blockIdx.x;
    const int sw   = (flat & 7) * 64 + (flat >> 3);
    const int bh   = sw >> 4;
    const int bx   = sw & 15;
    const int b    = bh >> 4;
    const int h    = bh & 15;
    const int q0w  = bx * 128 + wid * 16;

    *(f32x4*)&mtab[tid * 4] = *(const f32x4*)&mask_tab[tid * 4];

    const size_t head_off = (size_t)bh * S_LEN * DK;
    const unsigned short* qp = qh + head_off;
    const unsigned short* kp = kh + head_off;
    const unsigned short* vp = vh + head_off;

    s16x8 aq[2];
    {
        const unsigned short* qrow = qp + (size_t)(q0w + c) * DK;
        aq[0] = *(const s16x8*)(qrow + g * 8);
        aq[1] = *(const s16x8*)(qrow + 32 + g * 8);
    }

    f32x4 acc_o[4];
#pragma unroll
    for (int nf = 0; nf < 4; ++nf) acc_o[nf] = (f32x4){0.f, 0.f, 0.f, 0.f};
    float m_l = -1e30f;
    f32x4 lsum = (f32x4){0.f, 0.f, 0.f, 0.f};

    const int srowK = tid >> 3;
    const int soffE = (tid & 7) * 8;
    const int vd0   = (tid & 31) * 2;
    const int vkq   = (tid >> 5) * 4;

    s16x8 kreg;
    unsigned vreg[4];
    kreg = *(const s16x8*)&kp[(size_t)srowK * DK + soffE];
#pragma unroll
    for (int i = 0; i < 4; ++i)
        vreg[i] = *(const unsigned*)&vp[(size_t)(vkq + i) * DK + vd0];

    unsigned short* Ptw = Pt[wid];

    for (int kt = 0; kt < S_LEN / 64; ++kt) {
        const int k0 = kt * 64;
        __syncthreads();

        // ---- staged registers -> LDS ----
        *(s16x8*)((char*)Kt + srowK * 128 + ((soffE * 2) ^ ((srowK & 7) << 4))) = kreg;
        {
            u16x4 lo4, hi4;
#pragma unroll
            for (int i = 0; i < 4; ++i) {
                lo4[i] = (unsigned short)vreg[i];
                hi4[i] = (unsigned short)(vreg[i] >> 16);
            }
            *(u16x4*)((char*)Vt + vd0 * 128 + ((vkq * 2) ^ VSWZ(vd0))) = lo4;
            *(u16x4*)((char*)Vt + (vd0 + 1) * 128 +
                      ((vkq * 2) ^ VSWZ(vd0 + 1))) = hi4;
        }
        // ---- prefetch next tile (regs; spans barrier, waits at use) ----
        if (kt < S_LEN / 64 - 1) {
            const int k1 = k0 + 64;
            kreg = *(const s16x8*)&kp[(size_t)(k1 + srowK) * DK + soffE];
#pragma unroll
            for (int i = 0; i < 4; ++i)
                vreg[i] = *(const unsigned*)&vp[(size_t)(k1 + vkq + i) * DK + vd0];
        }
        __syncthreads();

        // ---- QK^T (swapped): lane holds q=c, k = nf*16+g*4+r ----
        f32x4 st[4];
        __builtin_amdgcn_s_setprio(1);
#pragma unroll
        for (int nf = 0; nf < 4; ++nf) {
            st[nf] = (f32x4){0.f, 0.f, 0.f, 0.f};
#pragma unroll
            for (int f = 0; f < 2; ++f) {
                const int row = nf * 16 + c;
                s16x8 kf = *(const s16x8*)((const char*)Kt + row * 128 +
                                           ((f * 64 + g * 16) ^ ((row & 7) << 4)));
                st[nf] = __builtin_amdgcn_mfma_f32_16x16x32_bf16(
                    kf, aq[f], st[nf], 0, 0, 0);
            }
        }
        __builtin_amdgcn_s_setprio(0);

        // ---- mask add (near-diagonal tiles only) ----
        const int diff = q0w - k0;
        if (diff >= -15 && diff <= 510) {
            const int dbase = q0w + c - k0;
#pragma unroll
            for (int nf = 0; nf < 4; ++nf) {
#pragma unroll
                for (int r = 0; r < 4; ++r) {
                    const int d = dbase - (nf * 16 + g * 4 + r);
                    if (d >= 0) st[nf][r] += mtab[d];
                }
            }
        }

        // ---- local tile max via v_max3 (cross-lane deferred) ----
        float tm = max3f(st[0][0], st[0][1], st[0][2]);
        tm = max3f(tm, st[0][3], st[1][0]);
        tm = max3f(tm, st[1][1], st[1][2]);
        tm = max3f(tm, st[1][3], st[2][0]);
        tm = max3f(tm, st[2][1], st[2][2]);
        tm = max3f(tm, st[2][3], st[3][0]);
        tm = max3f(tm, st[3][1], st[3][2]);
        tm = fmaxf(tm, st[3][3]);

        // ---- defer-max (T13): rescale only when max grew past THR=8 ----
        if (__any(tm > m_l + 8.0f)) {
            tm = fmaxf(tm, __shfl_xor(tm, 16));
            tm = fmaxf(tm, __shfl_xor(tm, 32));
            const float mnew = fmaxf(m_l, tm);
            const float csc  = fast_exp2(m_l - mnew);
            m_l = mnew;
            lsum *= csc;
            f32x4 cscv;
#pragma unroll
            for (int r = 0; r < 4; ++r) cscv[r] = __shfl(csc, g * 4 + r);
#pragma unroll
            for (int nf = 0; nf < 4; ++nf) acc_o[nf] *= cscv;
        }

        // ---- P = exp2(st - m); deferred l accumulation ----
#pragma unroll
        for (int nf = 0; nf < 4; ++nf)
#pragma unroll
            for (int r = 0; r < 4; ++r)
                st[nf][r] = fast_exp2(st[nf][r] - m_l);
        lsum += (st[0] + st[1]) + (st[2] + st[3]);

        // ---- P store: 2x cvt_pk -> one b64 per nf ----
#pragma unroll
        for (int nf = 0; nf < 4; ++nf) {
            u32x2 pk;
            pk[0] = cvt_pk_bf16(st[nf][0], st[nf][1]);
            pk[1] = cvt_pk_bf16(st[nf][2], st[nf][3]);
            *(u32x2*)((char*)Ptw + c * 128 +
                      ((nf * 32 + g * 8) ^ ((c & 7) << 4))) = pk;
        }

        // ---- PV: O[q][d] += P @ V ----
        __builtin_amdgcn_s_setprio(1);
#pragma unroll
        for (int f = 0; f < 2; ++f) {
            s16x8 pa = *(const s16x8*)((const char*)Ptw + c * 128 +
                                       ((f * 64 + g * 16) ^ ((c & 7) << 4)));
#pragma unroll
            for (int nf = 0; nf < 4; ++nf) {
                const int row = nf * 16 + c;
                s16x8 vb = *(const s16x8*)((const char*)Vt + row * 128 +
                                           ((f * 64 + g * 16) ^ VSWZ(row)));
                acc_o[nf] = __builtin_amdgcn_mfma_f32_16x16x32_bf16(
                    pa, vb, acc_o[nf], 0, 0, 0);
            }
        }
        __builtin_amdgcn_s_setprio(0);
    }

    // epilogue: reduce deferred l, normalize, store bf16
    float l = (lsum[0] + lsum[1]) + (lsum[2] + lsum[3]);
    l += __shfl_xor(l, 16);
    l += __shfl_xor(l, 32);
    f32x4 linv;
#pragma unroll
    for (int r = 0; r < 4; ++r) linv[r] = 1.0f / __shfl(l, g * 4 + r);
#pragma unroll
    for (int nf = 0; nf < 4; ++nf) {
#pragma unroll
        for (int r = 0; r < 4; ++r) {
            const int i_glob = q0w + g * 4 + r;
            const int d = nf * 16 + c;
            attn_out[((size_t)(b * S_LEN + i_glob)) * D_MODEL + h * DK + d] =
                f2bf(acc_o[nf][r] * linv[r]);
        }
    }
}

// ---------------------------------------------------------------------------
extern "C" void kernel_launch(void* const* d_in, const int* in_sizes, int n_in,
                              void* d_out, int out_size, void* d_ws, size_t ws_size,
                              hipStream_t stream) {
    const float* Q  = (const float*)d_in[0];
    const float* K  = (const float*)d_in[1];
    const float* V  = (const float*)d_in[2];
    const float* Wq = (const float*)d_in[3];
    const float* bq = (const float*)d_in[4];
    const float* Wk = (const float*)d_in[5];
    const float* bk = (const float*)d_in[6];
    const float* Wv = (const float*)d_in[7];
    const float* bv = (const float*)d_in[8];
    const float* Wo = (const float*)d_in[9];
    const float* bo = (const float*)d_in[10];
    float* out = (float*)d_out;

    const size_t XE = (size_t)M_ROWS * D_MODEL;
    const size_t WE = (size_t)D_MODEL * D_MODEL;
    unsigned short* qh  = (unsigned short*)d_ws;
    unsigned short* kh  = qh + XE;
    unsigned short* vh  = kh + XE;
    unsigned short* ah  = vh + XE;
    unsigned short* Qb  = ah + XE;
    unsigned short* Kb  = Qb + XE;
    unsigned short* Vb  = Kb + XE;
    unsigned short* Wqb = Vb + XE;
    unsigned short* Wkb = Wqb + WE;
    unsigned short* Wvb = Wkb + WE;
    unsigned short* Wob = Wvb + WE;
    float* mtab = (float*)(Wob + WE);

    // convert (+ fused mask tail): 8192 data blocks + 8 mask blocks
    convert_kernel<<<dim3((3 * XE / 8 + 4 * WE / 8) / 256 + 8), 256, 0, stream>>>(
        Q, K, V, Wq, Wk, Wv, Wo, Qb, Kb, Vb, Wqb, Wkb, Wvb, Wob, mtab);
    proj_gemm<<<dim3(32, 8, 3), 256, 0, stream>>>(
        Qb, Kb, Vb, Wqb, Wkb, Wvb, bq, bk, bv, qh, kh, vh);
    attn_kernel<<<dim3(16, 32), 512, 0, stream>>>(
        qh, kh, vh, mtab, ah);
    out_gemm<<<dim3(32, 8), 256, 0, stream>>>(
        ah, Wob, bo, out);
}